// Round 8
// baseline (666.208 us; speedup 1.0000x reference)
//
#include <hip/hip_runtime.h>
#include <hip/hip_bf16.h>

#define IN_DIM 128
#define OUT_DIM 256
#define KDIM 256            // 2*IN_DIM
#define EPS 1e-12f
#define CB_NODES 128        // nodes per coarse bucket
#define NB_MAX 1024         // max coarse buckets (N<=131072)
#define CAP_B 2560          // fixed slots per bucket (mean ~2046, max ~2270)

typedef __attribute__((ext_vector_type(8))) short short8;   // 8 bf16
typedef __attribute__((ext_vector_type(4))) float f32x4;

static __device__ __forceinline__ unsigned short f2bf(float f) {
  __hip_bfloat16 h = __float2bfloat16(f);   // RNE
  return *reinterpret_cast<unsigned short*>(&h);
}
static __device__ __forceinline__ unsigned pack2bf(float a, float b) {
  return (unsigned)f2bf(a) | ((unsigned)f2bf(b) << 16);
}
static __device__ __forceinline__ float bf_lo(unsigned v) {
  return __uint_as_float((v & 0xffffu) << 16);
}
static __device__ __forceinline__ float bf_hi(unsigned v) {
  return __uint_as_float(v & 0xffff0000u);
}

// ---------------------------------------------------------------------------
// Convert x (f32 [N][128]) into cols 0..127 of hb (bf16 [Mpad][256]).
// ---------------------------------------------------------------------------
__global__ __launch_bounds__(256) void cvt_x(
    const float* __restrict__ x, unsigned short* __restrict__ hb, int N) {
  const int total = N * 32;                 // N*128/4
  const int stride = gridDim.x * blockDim.x;
  for (int idx = blockIdx.x * blockDim.x + threadIdx.x; idx < total; idx += stride) {
    const int row = idx >> 5;
    const int c4 = (idx & 31) * 4;
    const float4 v = *reinterpret_cast<const float4*>(x + (size_t)row * IN_DIM + c4);
    ushort4 o;
    o.x = f2bf(v.x); o.y = f2bf(v.y); o.z = f2bf(v.z); o.w = f2bf(v.w);
    *reinterpret_cast<ushort4*>(hb + (size_t)row * KDIM + c4) = o;
  }
}

// ---------------------------------------------------------------------------
// Convert W (f32 [256][256]) -> Wb (bf16, same layout).
// ---------------------------------------------------------------------------
__global__ __launch_bounds__(256) void cvt_w(
    const float* __restrict__ W, unsigned short* __restrict__ Wb) {
  const int base = (blockIdx.x * blockDim.x + threadIdx.x) * 4;
  const float4 v = *reinterpret_cast<const float4*>(W + base);
  ushort4 o;
  o.x = f2bf(v.x); o.y = f2bf(v.y); o.z = f2bf(v.z); o.w = f2bf(v.w);
  *reinterpret_cast<ushort4*>(Wb + base) = o;
}

// ---------------------------------------------------------------------------
// One-pass partition into fixed-stride bucket regions. Per edge: one
// returning int atomic on cnt[src>>7] (782 L2-hot counters) + one 8B store
// into recs[b*CAP_B + p]. No histogram, no scan, no reserve phase.
// Record: x = dst | (src&127)<<17,  y = weight bits.
// Overflow (p >= CAP_B): record dropped; cagg_slow recomputes that bucket.
// ---------------------------------------------------------------------------
__global__ __launch_bounds__(256) void cpart1(
    const int* __restrict__ src, const int* __restrict__ dst,
    const float* __restrict__ ew,
    int* __restrict__ cnt, int2* __restrict__ recs, int E) {
  const int stride = gridDim.x * blockDim.x;
  for (int e = blockIdx.x * blockDim.x + threadIdx.x; e < E; e += stride) {
    const int s = src[e];
    const int b = s >> 7;
    const int p = atomicAdd(&cnt[b], 1);
    if (p < CAP_B) {
      int2 r;
      r.x = dst[e] | ((s & 127) << 17);
      r.y = __float_as_int(ew[e]);
      recs[(size_t)b * CAP_B + p] = r;
    }
  }
}

// ---------------------------------------------------------------------------
// Aggregate fast path: bucket fits CAP_B (always for this input).
// LDS counting sort by local node id, then wave wv owns nodes [16wv,16wv+16).
// Edge processing is 16-lanes-per-edge: g=lane>>4 selects the edge, fl=lane&15
// loads 16B (8 feats) -> one VMEM instruction serves 4 edges; main loop keeps
// 16 edges in flight. __shfl_xor(16/32) combines the 4 groups per node.
// ---------------------------------------------------------------------------
__global__ __launch_bounds__(512, 8) void cagg_fast(
    unsigned short* __restrict__ hb,
    const int* __restrict__ cnt,
    const int2* __restrict__ recs, int N) {
  __shared__ int2 lrec[CAP_B];               // 20 KB
  __shared__ int lstart[CB_NODES + 1];
  __shared__ int lcur[CB_NODES];
  const int tid = threadIdx.x;
  const int lane = tid & 63;
  const int wv = tid >> 6;                   // 0..7
  const int blk = blockIdx.x;
  const int m = cnt[blk];
  if (m > CAP_B) return;                     // rare: handled by cagg_slow
  const size_t rbase = (size_t)blk * CAP_B;

  if (tid < CB_NODES) lcur[tid] = 0;
  __syncthreads();
  for (int i = tid; i < m; i += 512)
    atomicAdd(&lcur[recs[rbase + i].x >> 17], 1);
  __syncthreads();
  if (wv == 0) {
    int carry = 0;
#pragma unroll
    for (int rr = 0; rr < 2; ++rr) {
      const int idx = rr * 64 + lane;
      const int c = lcur[idx];
      int incl = c;
#pragma unroll
      for (int d = 1; d < 64; d <<= 1) {
        int t = __shfl_up(incl, d, 64);
        if (lane >= d) incl += t;
      }
      lstart[idx] = carry + incl - c;
      carry += __shfl(incl, 63, 64);
    }
    if (lane == 0) lstart[CB_NODES] = carry;
  }
  __syncthreads();
  if (tid < CB_NODES) lcur[tid] = lstart[tid];
  __syncthreads();
  for (int i = tid; i < m; i += 512) {
    const int2 r = recs[rbase + i];
    lrec[atomicAdd(&lcur[r.x >> 17], 1)] = r;
  }
  __syncthreads();

  const int g = lane >> 4;                   // edge subgroup 0..3
  const int fl = lane & 15;                  // feature sub-lane (8 feats)
  for (int n = 0; n < 16; ++n) {
    const int rs = lstart[wv * 16 + n];
    const int re = lstart[wv * 16 + n + 1];
    float a0 = 0.f, a1 = 0.f, a2 = 0.f, a3 = 0.f;
    float a4 = 0.f, a5 = 0.f, a6 = 0.f, a7 = 0.f, ws = 0.f;
    int j0 = rs;
    for (; j0 + 16 <= re; j0 += 16) {        // 16 edges/iter: group g takes j0+g+4k
      const int e = j0 + g;
      const int2 r0 = lrec[e];
      const int2 r1 = lrec[e + 4];
      const int2 r2 = lrec[e + 8];
      const int2 r3 = lrec[e + 12];
      const uint4 v0 = *reinterpret_cast<const uint4*>(hb + (size_t)(r0.x & 0x1FFFF) * KDIM + fl * 8);
      const uint4 v1 = *reinterpret_cast<const uint4*>(hb + (size_t)(r1.x & 0x1FFFF) * KDIM + fl * 8);
      const uint4 v2 = *reinterpret_cast<const uint4*>(hb + (size_t)(r2.x & 0x1FFFF) * KDIM + fl * 8);
      const uint4 v3 = *reinterpret_cast<const uint4*>(hb + (size_t)(r3.x & 0x1FFFF) * KDIM + fl * 8);
      const float w0 = __int_as_float(r0.y), w1 = __int_as_float(r1.y);
      const float w2 = __int_as_float(r2.y), w3 = __int_as_float(r3.y);
      a0 += bf_lo(v0.x) * w0 + bf_lo(v1.x) * w1 + bf_lo(v2.x) * w2 + bf_lo(v3.x) * w3;
      a1 += bf_hi(v0.x) * w0 + bf_hi(v1.x) * w1 + bf_hi(v2.x) * w2 + bf_hi(v3.x) * w3;
      a2 += bf_lo(v0.y) * w0 + bf_lo(v1.y) * w1 + bf_lo(v2.y) * w2 + bf_lo(v3.y) * w3;
      a3 += bf_hi(v0.y) * w0 + bf_hi(v1.y) * w1 + bf_hi(v2.y) * w2 + bf_hi(v3.y) * w3;
      a4 += bf_lo(v0.z) * w0 + bf_lo(v1.z) * w1 + bf_lo(v2.z) * w2 + bf_lo(v3.z) * w3;
      a5 += bf_hi(v0.z) * w0 + bf_hi(v1.z) * w1 + bf_hi(v2.z) * w2 + bf_hi(v3.z) * w3;
      a6 += bf_lo(v0.w) * w0 + bf_lo(v1.w) * w1 + bf_lo(v2.w) * w2 + bf_lo(v3.w) * w3;
      a7 += bf_hi(v0.w) * w0 + bf_hi(v1.w) * w1 + bf_hi(v2.w) * w2 + bf_hi(v3.w) * w3;
      ws += w0 + w1 + w2 + w3;
    }
    for (; j0 < re; j0 += 4) {               // tail: <=15 edges, predicated
      const int e = j0 + g;
      const bool act = e < re;
      const int2 r = lrec[act ? e : rs];     // rs valid (run non-empty here)
      const float w = act ? __int_as_float(r.y) : 0.f;
      const uint4 v = *reinterpret_cast<const uint4*>(hb + (size_t)(r.x & 0x1FFFF) * KDIM + fl * 8);
      a0 += bf_lo(v.x) * w; a1 += bf_hi(v.x) * w;
      a2 += bf_lo(v.y) * w; a3 += bf_hi(v.y) * w;
      a4 += bf_lo(v.z) * w; a5 += bf_hi(v.z) * w;
      a6 += bf_lo(v.w) * w; a7 += bf_hi(v.w) * w;
      ws += w;
    }
    // combine the 4 edge-groups (lanes fl, fl+16, fl+32, fl+48)
    a0 += __shfl_xor(a0, 16, 64); a0 += __shfl_xor(a0, 32, 64);
    a1 += __shfl_xor(a1, 16, 64); a1 += __shfl_xor(a1, 32, 64);
    a2 += __shfl_xor(a2, 16, 64); a2 += __shfl_xor(a2, 32, 64);
    a3 += __shfl_xor(a3, 16, 64); a3 += __shfl_xor(a3, 32, 64);
    a4 += __shfl_xor(a4, 16, 64); a4 += __shfl_xor(a4, 32, 64);
    a5 += __shfl_xor(a5, 16, 64); a5 += __shfl_xor(a5, 32, 64);
    a6 += __shfl_xor(a6, 16, 64); a6 += __shfl_xor(a6, 32, 64);
    a7 += __shfl_xor(a7, 16, 64); a7 += __shfl_xor(a7, 32, 64);
    ws += __shfl_xor(ws, 16, 64); ws += __shfl_xor(ws, 32, 64);
    const int node = blk * CB_NODES + wv * 16 + n;
    if (g == 0 && node < N) {
      const float inv = 1.0f / fmaxf(ws, EPS);
      uint4 o;
      o.x = pack2bf(a0 * inv, a1 * inv);
      o.y = pack2bf(a2 * inv, a3 * inv);
      o.z = pack2bf(a4 * inv, a5 * inv);
      o.w = pack2bf(a6 * inv, a7 * inv);
      *reinterpret_cast<uint4*>(hb + (size_t)node * KDIM + IN_DIM + fl * 8) = o;
    }
  }
}

// ---------------------------------------------------------------------------
// Slow path: bucket overflowed CAP_B (never, for this input). Recompute the
// whole bucket from the raw edge arrays with LDS f32 atomics. Early-exit
// sweep otherwise.
// ---------------------------------------------------------------------------
__global__ __launch_bounds__(512) void cagg_slow(
    unsigned short* __restrict__ hb, const int* __restrict__ cnt,
    const int* __restrict__ src, const int* __restrict__ dstv,
    const float* __restrict__ ew, int N, int E) {
  const int blk = blockIdx.x;
  if (cnt[blk] <= CAP_B) return;
  __shared__ float agg[CB_NODES][IN_DIM];    // 64 KB
  __shared__ float wsum[CB_NODES];
  const int tid = threadIdx.x;
  const int lane = tid & 63;
  const int wv = tid >> 6;
  for (int i = tid; i < CB_NODES * IN_DIM; i += 512) (&agg[0][0])[i] = 0.f;
  if (tid < CB_NODES) wsum[tid] = 0.f;
  __syncthreads();
  for (int i = wv; i < E; i += 8) {          // one edge per wave
    const int s = src[i];
    if ((s >> 7) != blk) continue;
    const int sl = s & 127;
    const float w = ew[i];
    const unsigned v = *reinterpret_cast<const unsigned*>(
        hb + (size_t)dstv[i] * KDIM + lane * 2);
    atomicAdd(&agg[sl][lane * 2], bf_lo(v) * w);
    atomicAdd(&agg[sl][lane * 2 + 1], bf_hi(v) * w);
    if (lane == 0) atomicAdd(&wsum[sl], w);
  }
  __syncthreads();
  for (int n = 0; n < 16; ++n) {
    const int row = wv * 16 + n;
    const int node = blk * CB_NODES + row;
    if (node < N) {
      const float mm = fmaxf(wsum[row], EPS);
      *reinterpret_cast<unsigned*>(hb + (size_t)node * KDIM + IN_DIM + lane * 2) =
          pack2bf(agg[row][lane * 2] / mm, agg[row][lane * 2 + 1] / mm);
    }
  }
}

// ---------------------------------------------------------------------------
// MFMA GEMM: out = relu(hb @ Wb^T + b). Block = 256 rows x 256 cols, 8 waves.
// Wb (bf16) staged into LDS with XOR swizzle; A-frags preloaded to regs.
// ---------------------------------------------------------------------------
__global__ __launch_bounds__(512, 2) void sage_gemm_mfma(
    const unsigned short* __restrict__ hb,
    const unsigned short* __restrict__ Wb,
    const float* __restrict__ bias,
    float* __restrict__ out, int N) {
  __shared__ unsigned short Wl[OUT_DIM * KDIM];   // 128 KB, swizzled
  const int tid = threadIdx.x;
  const int lane = tid & 63;
  const int wv = tid >> 6;

  char* wl = reinterpret_cast<char*>(Wl);
  const uint4* wbv = reinterpret_cast<const uint4*>(Wb);
  for (int ch = tid; ch < OUT_DIM * KDIM / 8; ch += 512) {
    const int elem = ch * 8;
    const int j = elem >> 8;          // W row 0..255
    const int col = elem & 255;       // multiple of 8
    const uint4 o = wbv[ch];
    const int byte = (j << 9) | ((col * 2) ^ ((j & 7) << 4));
    *reinterpret_cast<uint4*>(wl + byte) = o;
  }

  const int row0 = blockIdx.x * 256 + wv * 32;
  const int kc = (lane >> 4) * 8;
  const unsigned short* arow0 = hb + (size_t)(row0 + (lane & 15)) * KDIM + kc;
  const unsigned short* arow1 = arow0 + 16 * KDIM;
  short8 a0[8], a1[8];
#pragma unroll
  for (int kk = 0; kk < 8; ++kk) {
    a0[kk] = *reinterpret_cast<const short8*>(arow0 + kk * 32);
    a1[kk] = *reinterpret_cast<const short8*>(arow1 + kk * 32);
  }

  __syncthreads();

  f32x4 acc[2][16];
#pragma unroll
  for (int i = 0; i < 2; ++i)
#pragma unroll
    for (int j = 0; j < 16; ++j) acc[i][j] = (f32x4){0.f, 0.f, 0.f, 0.f};

  const int jrow = lane & 15;
  const int kb0 = kc * 2;            // (lane>>4)*16
#pragma unroll
  for (int kk = 0; kk < 8; ++kk) {
    const int kbyte = kb0 + kk * 64;
#pragma unroll
    for (int ct = 0; ct < 16; ++ct) {
      const int j = ct * 16 + jrow;
      const short8 bf = *reinterpret_cast<const short8*>(
          wl + ((j << 9) | (kbyte ^ ((j & 7) << 4))));
      acc[0][ct] = __builtin_amdgcn_mfma_f32_16x16x32_bf16(a0[kk], bf, acc[0][ct], 0, 0, 0);
      acc[1][ct] = __builtin_amdgcn_mfma_f32_16x16x32_bf16(a1[kk], bf, acc[1][ct], 0, 0, 0);
    }
  }

  const int col = lane & 15;
  const int rquad = (lane >> 4) * 4;
#pragma unroll
  for (int ct = 0; ct < 16; ++ct) {
    const int j = ct * 16 + col;
    const float bj = bias[j];
#pragma unroll
    for (int rt = 0; rt < 2; ++rt) {
      const int rbase = row0 + rt * 16 + rquad;
      const f32x4 a = acc[rt][ct];
#pragma unroll
      for (int r = 0; r < 4; ++r) {
        const int row = rbase + r;
        if (row < N) out[(size_t)row * OUT_DIM + j] = fmaxf(a[r] + bj, 0.f);
      }
    }
  }
}

extern "C" void kernel_launch(void* const* d_in, const int* in_sizes, int n_in,
                              void* d_out, int out_size, void* d_ws, size_t ws_size,
                              hipStream_t stream) {
  const float* x  = (const float*)d_in[0];
  const int*   ei = (const int*)d_in[1];     // [2][E]
  const float* ew = (const float*)d_in[2];   // [E]
  const float* W  = (const float*)d_in[3];   // [OUT_DIM][KDIM]
  const float* b  = (const float*)d_in[4];   // [OUT_DIM]
  float* out = (float*)d_out;

  const int N = in_sizes[0] / IN_DIM;        // 100000
  const int E = in_sizes[2];                 // 1600000
  const int* src = ei;
  const int* dst = ei + E;

  const int gemm_blocks = (N + 255) / 256;   // 391
  const int Mpad = gemm_blocks * 256;        // 100096
  const int NB = (N + CB_NODES - 1) / CB_NODES;   // 782

  // ws layout (4-byte elems):
  //   hb[Mpad][256] bf16 | Wb[256][256] bf16 | recs[NB*CAP_B] int2 | cnt[NB_MAX]
  unsigned short* hb = (unsigned short*)d_ws;
  unsigned short* Wb = hb + (size_t)Mpad * KDIM;
  int2* recs = (int2*)(Wb + OUT_DIM * KDIM);
  int* cnt   = (int*)(recs + (size_t)NB * CAP_B);

  hipMemsetAsync(cnt, 0, NB_MAX * sizeof(int), stream);

  cvt_x<<<2048, 256, 0, stream>>>(x, hb, N);
  cvt_w<<<OUT_DIM * KDIM / 4 / 256, 256, 0, stream>>>(W, Wb);
  cpart1<<<2048, 256, 0, stream>>>(src, dst, ew, cnt, recs, E);
  cagg_fast<<<NB, 512, 0, stream>>>(hb, cnt, recs, N);
  cagg_slow<<<NB, 512, 0, stream>>>(hb, cnt, src, dst, ew, N, E);
  sage_gemm_mfma<<<gemm_blocks, 512, 0, stream>>>(hb, Wb, b, out, N);
}

// Round 10
// 382.069 us; speedup vs baseline: 1.7437x; 1.7437x over previous
//
#include <hip/hip_runtime.h>
#include <hip/hip_bf16.h>

#define IN_DIM 128
#define OUT_DIM 256
#define KDIM 256            // 2*IN_DIM
#define EPS 1e-12f
#define CB_NODES 128        // nodes per coarse bucket
#define NB_MAX 1024         // max coarse buckets (N<=131072)
#define PART_CHUNK 2048     // 782 partition blocks, measured best (r7: 68.7us)
#define CAP 2560            // records per LDS chunk (mean bucket ~2046, max ~2270)

typedef __attribute__((ext_vector_type(8))) short short8;   // 8 bf16
typedef __attribute__((ext_vector_type(4))) float f32x4;

static __device__ __forceinline__ unsigned short f2bf(float f) {
  __hip_bfloat16 h = __float2bfloat16(f);   // RNE
  return *reinterpret_cast<unsigned short*>(&h);
}
static __device__ __forceinline__ unsigned pack2bf(float a, float b) {
  return (unsigned)f2bf(a) | ((unsigned)f2bf(b) << 16);
}
static __device__ __forceinline__ float bf_lo(unsigned v) {
  return __uint_as_float((v & 0xffffu) << 16);
}
static __device__ __forceinline__ float bf_hi(unsigned v) {
  return __uint_as_float(v & 0xffff0000u);
}

// ---------------------------------------------------------------------------
// Convert x (f32 [N][128]) into cols 0..127 of hb (bf16 [Mpad][256]).
// ---------------------------------------------------------------------------
__global__ __launch_bounds__(256) void cvt_x(
    const float* __restrict__ x, unsigned short* __restrict__ hb, int N) {
  const int total = N * 32;                 // N*128/4
  const int stride = gridDim.x * blockDim.x;
  for (int idx = blockIdx.x * blockDim.x + threadIdx.x; idx < total; idx += stride) {
    const int row = idx >> 5;
    const int c4 = (idx & 31) * 4;
    const float4 v = *reinterpret_cast<const float4*>(x + (size_t)row * IN_DIM + c4);
    ushort4 o;
    o.x = f2bf(v.x); o.y = f2bf(v.y); o.z = f2bf(v.z); o.w = f2bf(v.w);
    *reinterpret_cast<ushort4*>(hb + (size_t)row * KDIM + c4) = o;
  }
}

// ---------------------------------------------------------------------------
// Convert W (f32 [256][256]) -> Wb (bf16, same layout).
// ---------------------------------------------------------------------------
__global__ __launch_bounds__(256) void cvt_w(
    const float* __restrict__ W, unsigned short* __restrict__ Wb) {
  const int base = (blockIdx.x * blockDim.x + threadIdx.x) * 4;
  const float4 v = *reinterpret_cast<const float4*>(W + base);
  ushort4 o;
  o.x = f2bf(v.x); o.y = f2bf(v.y); o.z = f2bf(v.z); o.w = f2bf(v.w);
  *reinterpret_cast<ushort4*>(Wb + base) = o;
}

// ---------------------------------------------------------------------------
// Coarse histogram: cnt[src>>7]++ via per-block LDS hist, then merge.
// ---------------------------------------------------------------------------
__global__ __launch_bounds__(256) void chist(
    const int* __restrict__ src, int* __restrict__ cnt, int E, int NB) {
  __shared__ int lcnt[NB_MAX];
  for (int i = threadIdx.x; i < NB; i += 256) lcnt[i] = 0;
  __syncthreads();
  const int stride = gridDim.x * blockDim.x;
  for (int e = blockIdx.x * blockDim.x + threadIdx.x; e < E; e += stride)
    atomicAdd(&lcnt[src[e] >> 7], 1);
  __syncthreads();
  for (int i = threadIdx.x; i < NB; i += 256)
    if (lcnt[i]) atomicAdd(&cnt[i], lcnt[i]);
}

// ---------------------------------------------------------------------------
// Exclusive scan of cnt -> bstart[NB+1]; init gcursor = bstart. One wave.
// ---------------------------------------------------------------------------
__global__ void cscan(const int* __restrict__ cnt, int* __restrict__ bstart,
                      int* __restrict__ gcursor, int NB) {
  const int lane = threadIdx.x;   // 64 threads
  int carry = 0;
  for (int base = 0; base < NB; base += 64) {
    const int i = base + lane;
    const int c = (i < NB) ? cnt[i] : 0;
    int incl = c;
    for (int d = 1; d < 64; d <<= 1) {
      int t = __shfl_up(incl, d, 64);
      if (lane >= d) incl += t;
    }
    const int excl = carry + incl - c;
    if (i < NB) { bstart[i] = excl; gcursor[i] = excl; }
    carry += __shfl(incl, 63, 64);
  }
  if (lane == 0) bstart[NB] = carry;
}

// ---------------------------------------------------------------------------
// Partition edges into coarse buckets (r7 structure, measured 68.7us).
// Per-block LDS hist -> one global range-reservation atomic per
// (block,bucket) -> contiguous write runs. src values cached in LDS during
// pass 1 so the scatter pass skips the re-read.
// Record: x = dst | (src&127)<<17,  y = weight bits.
// ---------------------------------------------------------------------------
__global__ __launch_bounds__(256) void cpartition(
    const int* __restrict__ src, const int* __restrict__ dst,
    const float* __restrict__ ew,
    int* __restrict__ gcursor, int2* __restrict__ recs, int E, int NB) {
  __shared__ int pos[NB_MAX];
  __shared__ int ssrc[PART_CHUNK];           // 8 KB src cache
  const int c0 = blockIdx.x * PART_CHUNK;
  const int c1 = min(E, c0 + PART_CHUNK);
  for (int i = threadIdx.x; i < NB; i += 256) pos[i] = 0;
  __syncthreads();
  for (int i = c0 + threadIdx.x; i < c1; i += 256) {
    const int s = src[i];
    ssrc[i - c0] = s;
    atomicAdd(&pos[s >> 7], 1);
  }
  __syncthreads();
  for (int b = threadIdx.x; b < NB; b += 256) {
    const int c = pos[b];
    pos[b] = c ? atomicAdd(&gcursor[b], c) : 0;
  }
  __syncthreads();
  for (int i = c0 + threadIdx.x; i < c1; i += 256) {
    const int s = ssrc[i - c0];
    const int p = atomicAdd(&pos[s >> 7], 1);
    int2 r;
    r.x = dst[i] | ((s & 127) << 17);
    r.y = __float_as_int(ew[i]);
    recs[p] = r;
  }
}

// ---------------------------------------------------------------------------
// Aggregate fast path (bucket fits one CAP chunk — always for this input).
// LDS counting sort by local node id, then wave wv owns nodes [16wv,16wv+16).
// Edge processing is 16-lanes-per-edge: g=lane>>4 selects the edge, fl=lane&15
// loads 16B (8 feats) -> one VMEM instruction serves 4 edges; main loop keeps
// 16 edges in flight. __shfl_xor(16/32) combines the 4 groups per node.
// ---------------------------------------------------------------------------
__global__ __launch_bounds__(512, 8) void cagg_fast(
    unsigned short* __restrict__ hb,
    const int* __restrict__ bstart,
    const int2* __restrict__ recs, int N) {
  __shared__ int2 lrec[CAP];                 // 20 KB
  __shared__ int lstart[CB_NODES + 1];
  __shared__ int lcur[CB_NODES];
  const int tid = threadIdx.x;
  const int lane = tid & 63;
  const int wv = tid >> 6;                   // 0..7
  const int blk = blockIdx.x;
  const int e0 = bstart[blk];
  const int e1 = bstart[blk + 1];
  const int m = e1 - e0;
  if (m > CAP) return;                       // rare: handled by cagg_slow

  if (tid < CB_NODES) lcur[tid] = 0;
  __syncthreads();
  for (int i = tid; i < m; i += 512)
    atomicAdd(&lcur[recs[e0 + i].x >> 17], 1);
  __syncthreads();
  if (wv == 0) {
    int carry = 0;
#pragma unroll
    for (int rr = 0; rr < 2; ++rr) {
      const int idx = rr * 64 + lane;
      const int c = lcur[idx];
      int incl = c;
#pragma unroll
      for (int d = 1; d < 64; d <<= 1) {
        int t = __shfl_up(incl, d, 64);
        if (lane >= d) incl += t;
      }
      lstart[idx] = carry + incl - c;
      carry += __shfl(incl, 63, 64);
    }
    if (lane == 0) lstart[CB_NODES] = carry;
  }
  __syncthreads();
  if (tid < CB_NODES) lcur[tid] = lstart[tid];
  __syncthreads();
  for (int i = tid; i < m; i += 512) {
    const int2 r = recs[e0 + i];
    lrec[atomicAdd(&lcur[r.x >> 17], 1)] = r;
  }
  __syncthreads();

  const int g = lane >> 4;                   // edge subgroup 0..3
  const int fl = lane & 15;                  // feature sub-lane (8 feats)
  for (int n = 0; n < 16; ++n) {
    const int rs = lstart[wv * 16 + n];
    const int re = lstart[wv * 16 + n + 1];
    float a0 = 0.f, a1 = 0.f, a2 = 0.f, a3 = 0.f;
    float a4 = 0.f, a5 = 0.f, a6 = 0.f, a7 = 0.f, ws = 0.f;
    int j0 = rs;
    for (; j0 + 16 <= re; j0 += 16) {        // 16 edges/iter
      const int e = j0 + g;
      const int2 r0 = lrec[e];
      const int2 r1 = lrec[e + 4];
      const int2 r2 = lrec[e + 8];
      const int2 r3 = lrec[e + 12];
      const uint4 v0 = *reinterpret_cast<const uint4*>(hb + (size_t)(r0.x & 0x1FFFF) * KDIM + fl * 8);
      const uint4 v1 = *reinterpret_cast<const uint4*>(hb + (size_t)(r1.x & 0x1FFFF) * KDIM + fl * 8);
      const uint4 v2 = *reinterpret_cast<const uint4*>(hb + (size_t)(r2.x & 0x1FFFF) * KDIM + fl * 8);
      const uint4 v3 = *reinterpret_cast<const uint4*>(hb + (size_t)(r3.x & 0x1FFFF) * KDIM + fl * 8);
      const float w0 = __int_as_float(r0.y), w1 = __int_as_float(r1.y);
      const float w2 = __int_as_float(r2.y), w3 = __int_as_float(r3.y);
      a0 += bf_lo(v0.x) * w0 + bf_lo(v1.x) * w1 + bf_lo(v2.x) * w2 + bf_lo(v3.x) * w3;
      a1 += bf_hi(v0.x) * w0 + bf_hi(v1.x) * w1 + bf_hi(v2.x) * w2 + bf_hi(v3.x) * w3;
      a2 += bf_lo(v0.y) * w0 + bf_lo(v1.y) * w1 + bf_lo(v2.y) * w2 + bf_lo(v3.y) * w3;
      a3 += bf_hi(v0.y) * w0 + bf_hi(v1.y) * w1 + bf_hi(v2.y) * w2 + bf_hi(v3.y) * w3;
      a4 += bf_lo(v0.z) * w0 + bf_lo(v1.z) * w1 + bf_lo(v2.z) * w2 + bf_lo(v3.z) * w3;
      a5 += bf_hi(v0.z) * w0 + bf_hi(v1.z) * w1 + bf_hi(v2.z) * w2 + bf_hi(v3.z) * w3;
      a6 += bf_lo(v0.w) * w0 + bf_lo(v1.w) * w1 + bf_lo(v2.w) * w2 + bf_lo(v3.w) * w3;
      a7 += bf_hi(v0.w) * w0 + bf_hi(v1.w) * w1 + bf_hi(v2.w) * w2 + bf_hi(v3.w) * w3;
      ws += w0 + w1 + w2 + w3;
    }
    for (; j0 < re; j0 += 4) {               // tail: <=15 edges, predicated
      const int e = j0 + g;
      const bool act = e < re;
      const int2 r = lrec[act ? e : rs];     // rs valid (run non-empty here)
      const float w = act ? __int_as_float(r.y) : 0.f;
      const uint4 v = *reinterpret_cast<const uint4*>(hb + (size_t)(r.x & 0x1FFFF) * KDIM + fl * 8);
      a0 += bf_lo(v.x) * w; a1 += bf_hi(v.x) * w;
      a2 += bf_lo(v.y) * w; a3 += bf_hi(v.y) * w;
      a4 += bf_lo(v.z) * w; a5 += bf_hi(v.z) * w;
      a6 += bf_lo(v.w) * w; a7 += bf_hi(v.w) * w;
      ws += w;
    }
    // combine the 4 edge-groups (lanes fl, fl+16, fl+32, fl+48)
    a0 += __shfl_xor(a0, 16, 64); a0 += __shfl_xor(a0, 32, 64);
    a1 += __shfl_xor(a1, 16, 64); a1 += __shfl_xor(a1, 32, 64);
    a2 += __shfl_xor(a2, 16, 64); a2 += __shfl_xor(a2, 32, 64);
    a3 += __shfl_xor(a3, 16, 64); a3 += __shfl_xor(a3, 32, 64);
    a4 += __shfl_xor(a4, 16, 64); a4 += __shfl_xor(a4, 32, 64);
    a5 += __shfl_xor(a5, 16, 64); a5 += __shfl_xor(a5, 32, 64);
    a6 += __shfl_xor(a6, 16, 64); a6 += __shfl_xor(a6, 32, 64);
    a7 += __shfl_xor(a7, 16, 64); a7 += __shfl_xor(a7, 32, 64);
    ws += __shfl_xor(ws, 16, 64); ws += __shfl_xor(ws, 32, 64);
    const int node = blk * CB_NODES + wv * 16 + n;
    if (g == 0 && node < N) {
      const float inv = 1.0f / fmaxf(ws, EPS);
      uint4 o;
      o.x = pack2bf(a0 * inv, a1 * inv);
      o.y = pack2bf(a2 * inv, a3 * inv);
      o.z = pack2bf(a4 * inv, a5 * inv);
      o.w = pack2bf(a6 * inv, a7 * inv);
      *reinterpret_cast<uint4*>(hb + (size_t)node * KDIM + IN_DIM + fl * 8) = o;
    }
  }
}

// ---------------------------------------------------------------------------
// Slow path: bucket > CAP (never for this input). Multi-chunk counting sort
// with persistent register accumulators. Early-exit sweep otherwise.
// ---------------------------------------------------------------------------
__global__ __launch_bounds__(512) void cagg_slow(
    unsigned short* __restrict__ hb,
    const int* __restrict__ bstart,
    const int2* __restrict__ recs, int N) {
  const int blk = blockIdx.x;
  const int e0 = bstart[blk];
  const int e1 = bstart[blk + 1];
  if (e1 - e0 <= CAP) return;                // handled by cagg_fast

  __shared__ int2 lrec[CAP];
  __shared__ int lstart[CB_NODES + 1];
  __shared__ int lcur[CB_NODES];
  const int tid = threadIdx.x;
  const int lane = tid & 63;
  const int wv = tid >> 6;

  float ax[16], ay[16], ws[16];
#pragma unroll
  for (int n = 0; n < 16; ++n) { ax[n] = 0.f; ay[n] = 0.f; ws[n] = 0.f; }

  for (int base = e0; base < e1; base += CAP) {
    const int m = min(CAP, e1 - base);
    if (tid < CB_NODES) lcur[tid] = 0;
    __syncthreads();
    for (int i = tid; i < m; i += 512)
      atomicAdd(&lcur[recs[base + i].x >> 17], 1);
    __syncthreads();
    if (wv == 0) {
      int carry = 0;
#pragma unroll
      for (int rr = 0; rr < 2; ++rr) {
        const int idx = rr * 64 + lane;
        const int c = lcur[idx];
        int incl = c;
#pragma unroll
        for (int d = 1; d < 64; d <<= 1) {
          int t = __shfl_up(incl, d, 64);
          if (lane >= d) incl += t;
        }
        lstart[idx] = carry + incl - c;
        carry += __shfl(incl, 63, 64);
      }
      if (lane == 0) lstart[CB_NODES] = carry;
    }
    __syncthreads();
    if (tid < CB_NODES) lcur[tid] = lstart[tid];
    __syncthreads();
    for (int i = tid; i < m; i += 512) {
      const int2 r = recs[base + i];
      lrec[atomicAdd(&lcur[r.x >> 17], 1)] = r;
    }
    __syncthreads();
#pragma unroll
    for (int n = 0; n < 16; ++n) {
      const int rs = lstart[wv * 16 + n];
      const int re = lstart[wv * 16 + n + 1];
      for (int j = rs; j < re; ++j) {
        const int2 r = lrec[j];
        const unsigned v = *reinterpret_cast<const unsigned*>(
            hb + (size_t)(r.x & 0x1FFFF) * KDIM + lane * 2);
        const float w = __int_as_float(r.y);
        ax[n] += bf_lo(v) * w;
        ay[n] += bf_hi(v) * w;
        ws[n] += w;
      }
    }
    __syncthreads();
  }

#pragma unroll
  for (int n = 0; n < 16; ++n) {
    const int node = blk * CB_NODES + wv * 16 + n;
    if (node < N) {
      const float mm = fmaxf(ws[n], EPS);
      *reinterpret_cast<unsigned*>(hb + (size_t)node * KDIM + IN_DIM + lane * 2) =
          pack2bf(ax[n] / mm, ay[n] / mm);
    }
  }
}

// ---------------------------------------------------------------------------
// MFMA GEMM: out = relu(hb @ Wb^T + b). Block = 256 rows x 256 cols, 8 waves.
// Wb (bf16) staged into LDS with XOR swizzle; A-frags preloaded to regs.
// ---------------------------------------------------------------------------
__global__ __launch_bounds__(512, 2) void sage_gemm_mfma(
    const unsigned short* __restrict__ hb,
    const unsigned short* __restrict__ Wb,
    const float* __restrict__ bias,
    float* __restrict__ out, int N) {
  __shared__ unsigned short Wl[OUT_DIM * KDIM];   // 128 KB, swizzled
  const int tid = threadIdx.x;
  const int lane = tid & 63;
  const int wv = tid >> 6;

  char* wl = reinterpret_cast<char*>(Wl);
  const uint4* wbv = reinterpret_cast<const uint4*>(Wb);
  for (int ch = tid; ch < OUT_DIM * KDIM / 8; ch += 512) {
    const int elem = ch * 8;
    const int j = elem >> 8;          // W row 0..255
    const int col = elem & 255;       // multiple of 8
    const uint4 o = wbv[ch];
    const int byte = (j << 9) | ((col * 2) ^ ((j & 7) << 4));
    *reinterpret_cast<uint4*>(wl + byte) = o;
  }

  const int row0 = blockIdx.x * 256 + wv * 32;
  const int kc = (lane >> 4) * 8;
  const unsigned short* arow0 = hb + (size_t)(row0 + (lane & 15)) * KDIM + kc;
  const unsigned short* arow1 = arow0 + 16 * KDIM;
  short8 a0[8], a1[8];
#pragma unroll
  for (int kk = 0; kk < 8; ++kk) {
    a0[kk] = *reinterpret_cast<const short8*>(arow0 + kk * 32);
    a1[kk] = *reinterpret_cast<const short8*>(arow1 + kk * 32);
  }

  __syncthreads();

  f32x4 acc[2][16];
#pragma unroll
  for (int i = 0; i < 2; ++i)
#pragma unroll
    for (int j = 0; j < 16; ++j) acc[i][j] = (f32x4){0.f, 0.f, 0.f, 0.f};

  const int jrow = lane & 15;
  const int kb0 = kc * 2;            // (lane>>4)*16
#pragma unroll
  for (int kk = 0; kk < 8; ++kk) {
    const int kbyte = kb0 + kk * 64;
#pragma unroll
    for (int ct = 0; ct < 16; ++ct) {
      const int j = ct * 16 + jrow;
      const short8 bf = *reinterpret_cast<const short8*>(
          wl + ((j << 9) | (kbyte ^ ((j & 7) << 4))));
      acc[0][ct] = __builtin_amdgcn_mfma_f32_16x16x32_bf16(a0[kk], bf, acc[0][ct], 0, 0, 0);
      acc[1][ct] = __builtin_amdgcn_mfma_f32_16x16x32_bf16(a1[kk], bf, acc[1][ct], 0, 0, 0);
    }
  }

  const int col = lane & 15;
  const int rquad = (lane >> 4) * 4;
#pragma unroll
  for (int ct = 0; ct < 16; ++ct) {
    const int j = ct * 16 + col;
    const float bj = bias[j];
#pragma unroll
    for (int rt = 0; rt < 2; ++rt) {
      const int rbase = row0 + rt * 16 + rquad;
      const f32x4 a = acc[rt][ct];
#pragma unroll
      for (int r = 0; r < 4; ++r) {
        const int row = rbase + r;
        if (row < N) out[(size_t)row * OUT_DIM + j] = fmaxf(a[r] + bj, 0.f);
      }
    }
  }
}

extern "C" void kernel_launch(void* const* d_in, const int* in_sizes, int n_in,
                              void* d_out, int out_size, void* d_ws, size_t ws_size,
                              hipStream_t stream) {
  const float* x  = (const float*)d_in[0];
  const int*   ei = (const int*)d_in[1];     // [2][E]
  const float* ew = (const float*)d_in[2];   // [E]
  const float* W  = (const float*)d_in[3];   // [OUT_DIM][KDIM]
  const float* b  = (const float*)d_in[4];   // [OUT_DIM]
  float* out = (float*)d_out;

  const int N = in_sizes[0] / IN_DIM;        // 100000
  const int E = in_sizes[2];                 // 1600000
  const int* src = ei;
  const int* dst = ei + E;

  const int gemm_blocks = (N + 255) / 256;   // 391
  const int Mpad = gemm_blocks * 256;        // 100096
  const int NB = (N + CB_NODES - 1) / CB_NODES;   // 782

  // ws layout (4-byte elems):
  //   hb[Mpad][256] bf16 | Wb[256][256] bf16 | recs[E] int2 |
  //   cnt[NB_MAX] | bstart[NB_MAX+1] | gcursor[NB_MAX]
  unsigned short* hb = (unsigned short*)d_ws;
  unsigned short* Wb = hb + (size_t)Mpad * KDIM;
  int2* recs   = (int2*)(Wb + OUT_DIM * KDIM);
  int* cnt     = (int*)(recs + E);
  int* bstart  = cnt + NB_MAX;
  int* gcursor = bstart + NB_MAX + 1;

  hipMemsetAsync(cnt, 0, NB * sizeof(int), stream);

  cvt_x<<<2048, 256, 0, stream>>>(x, hb, N);
  cvt_w<<<OUT_DIM * KDIM / 4 / 256, 256, 0, stream>>>(W, Wb);
  chist<<<512, 256, 0, stream>>>(src, cnt, E, NB);
  cscan<<<1, 64, 0, stream>>>(cnt, bstart, gcursor, NB);
  cpartition<<<(E + PART_CHUNK - 1) / PART_CHUNK, 256, 0, stream>>>(
      src, dst, ew, gcursor, recs, E, NB);
  cagg_fast<<<NB, 512, 0, stream>>>(hb, bstart, recs, N);
  cagg_slow<<<NB, 512, 0, stream>>>(hb, bstart, recs, N);
  sage_gemm_mfma<<<gemm_blocks, 512, 0, stream>>>(hb, Wb, b, out, N);
}

// Round 12
// 334.809 us; speedup vs baseline: 1.9898x; 1.1412x over previous
//
#include <hip/hip_runtime.h>
#include <hip/hip_bf16.h>

#define IN_DIM 128
#define OUT_DIM 256
#define KDIM 256            // 2*IN_DIM
#define EPS 1e-12f
#define CB_NODES 128        // nodes per coarse bucket
#define NB_MAX 1024         // max coarse buckets (N<=131072)
#define PART_CHUNK 4096     // 391 partition blocks x 512 thr (r10: 2048x256 = 71us)
#define CAP_B 2560          // fixed slots per bucket (mean ~2046, max ~2270)

typedef __attribute__((ext_vector_type(8))) short short8;   // 8 bf16
typedef __attribute__((ext_vector_type(4))) float f32x4;

static __device__ __forceinline__ unsigned short f2bf(float f) {
  __hip_bfloat16 h = __float2bfloat16(f);   // RNE
  return *reinterpret_cast<unsigned short*>(&h);
}
static __device__ __forceinline__ unsigned pack2bf(float a, float b) {
  return (unsigned)f2bf(a) | ((unsigned)f2bf(b) << 16);
}
static __device__ __forceinline__ float bf_lo(unsigned v) {
  return __uint_as_float((v & 0xffffu) << 16);
}
static __device__ __forceinline__ float bf_hi(unsigned v) {
  return __uint_as_float(v & 0xffff0000u);
}

// ---------------------------------------------------------------------------
// Init bucket-region cursors: gcursor[b] = b*CAP_B (absolute slot index).
// Replaces chist + cscan + memset.
// ---------------------------------------------------------------------------
__global__ __launch_bounds__(256) void ginit(int* __restrict__ gcursor, int NB) {
  const int b = blockIdx.x * blockDim.x + threadIdx.x;
  if (b < NB) gcursor[b] = b * CAP_B;
}

// ---------------------------------------------------------------------------
// Convert x (f32 [N][128]) into cols 0..127 of hb (bf16 [Mpad][256]).
// ---------------------------------------------------------------------------
__global__ __launch_bounds__(256) void cvt_x(
    const float* __restrict__ x, unsigned short* __restrict__ hb, int N) {
  const int total = N * 32;                 // N*128/4
  const int stride = gridDim.x * blockDim.x;
  for (int idx = blockIdx.x * blockDim.x + threadIdx.x; idx < total; idx += stride) {
    const int row = idx >> 5;
    const int c4 = (idx & 31) * 4;
    const float4 v = *reinterpret_cast<const float4*>(x + (size_t)row * IN_DIM + c4);
    ushort4 o;
    o.x = f2bf(v.x); o.y = f2bf(v.y); o.z = f2bf(v.z); o.w = f2bf(v.w);
    *reinterpret_cast<ushort4*>(hb + (size_t)row * KDIM + c4) = o;
  }
}

// ---------------------------------------------------------------------------
// Partition edges into fixed-stride bucket regions. Per-block LDS hist ->
// ONE range-reservation atomic per (block,bucket) on the region cursor ->
// contiguous ~42B write runs. Record: x = dst | (src&127)<<17, y = w bits.
// Overflow guard: slots past the bucket's region are dropped (cagg_slow
// recomputes that bucket from the raw edge list).
// ---------------------------------------------------------------------------
__global__ __launch_bounds__(512) void cpartition(
    const int* __restrict__ src, const int* __restrict__ dst,
    const float* __restrict__ ew,
    int* __restrict__ gcursor, int2* __restrict__ recs, int E, int NB) {
  __shared__ int pos[NB_MAX];
  __shared__ int ssrc[PART_CHUNK];           // 16 KB src cache
  const int tid = threadIdx.x;
  const int c0 = blockIdx.x * PART_CHUNK;
  const int c1 = min(E, c0 + PART_CHUNK);
  for (int i = tid; i < NB; i += 512) pos[i] = 0;
  __syncthreads();
  for (int i = c0 + tid; i < c1; i += 512) {
    const int s = src[i];
    ssrc[i - c0] = s;
    atomicAdd(&pos[s >> 7], 1);
  }
  __syncthreads();
  for (int b = tid; b < NB; b += 512) {
    const int c = pos[b];
    pos[b] = c ? atomicAdd(&gcursor[b], c) : 0;   // absolute slot base
  }
  __syncthreads();
  for (int i = c0 + tid; i < c1; i += 512) {
    const int s = ssrc[i - c0];
    const int b = s >> 7;
    const int p = atomicAdd(&pos[b], 1);     // absolute slot
    if (p < (b + 1) * CAP_B) {               // region overflow guard
      int2 r;
      r.x = dst[i] | ((s & 127) << 17);
      r.y = __float_as_int(ew[i]);
      recs[p] = r;
    }
  }
}

// ---------------------------------------------------------------------------
// Aggregate fast path: bucket fits its region (always for this input).
// LDS counting sort by local node id, then wave wv owns nodes [16wv,16wv+16).
// 16-lanes-per-edge: g=lane>>4 picks the edge, fl=lane&15 loads 16B (8
// feats) -> one VMEM instr serves 4 edges; 16 edges in flight. shfl_xor
// combines the 4 groups.
// ---------------------------------------------------------------------------
__global__ __launch_bounds__(512, 8) void cagg_fast(
    unsigned short* __restrict__ hb,
    const int* __restrict__ gcursor,
    const int2* __restrict__ recs, int N) {
  __shared__ int2 lrec[CAP_B];               // 20 KB
  __shared__ int lstart[CB_NODES + 1];
  __shared__ int lcur[CB_NODES];
  const int tid = threadIdx.x;
  const int lane = tid & 63;
  const int wv = tid >> 6;                   // 0..7
  const int blk = blockIdx.x;
  const int m = gcursor[blk] - blk * CAP_B;  // records in bucket
  if (m > CAP_B) return;                     // rare: handled by cagg_slow
  const size_t rbase = (size_t)blk * CAP_B;

  if (tid < CB_NODES) lcur[tid] = 0;
  __syncthreads();
  for (int i = tid; i < m; i += 512)
    atomicAdd(&lcur[recs[rbase + i].x >> 17], 1);
  __syncthreads();
  if (wv == 0) {
    int carry = 0;
#pragma unroll
    for (int rr = 0; rr < 2; ++rr) {
      const int idx = rr * 64 + lane;
      const int c = lcur[idx];
      int incl = c;
#pragma unroll
      for (int d = 1; d < 64; d <<= 1) {
        int t = __shfl_up(incl, d, 64);
        if (lane >= d) incl += t;
      }
      lstart[idx] = carry + incl - c;
      carry += __shfl(incl, 63, 64);
    }
    if (lane == 0) lstart[CB_NODES] = carry;
  }
  __syncthreads();
  if (tid < CB_NODES) lcur[tid] = lstart[tid];
  __syncthreads();
  for (int i = tid; i < m; i += 512) {
    const int2 r = recs[rbase + i];
    lrec[atomicAdd(&lcur[r.x >> 17], 1)] = r;
  }
  __syncthreads();

  const int g = lane >> 4;                   // edge subgroup 0..3
  const int fl = lane & 15;                  // feature sub-lane (8 feats)
  for (int n = 0; n < 16; ++n) {
    const int rs = lstart[wv * 16 + n];
    const int re = lstart[wv * 16 + n + 1];
    float a0 = 0.f, a1 = 0.f, a2 = 0.f, a3 = 0.f;
    float a4 = 0.f, a5 = 0.f, a6 = 0.f, a7 = 0.f, ws = 0.f;
    int j0 = rs;
    for (; j0 + 16 <= re; j0 += 16) {        // 16 edges/iter
      const int e = j0 + g;
      const int2 r0 = lrec[e];
      const int2 r1 = lrec[e + 4];
      const int2 r2 = lrec[e + 8];
      const int2 r3 = lrec[e + 12];
      const uint4 v0 = *reinterpret_cast<const uint4*>(hb + (size_t)(r0.x & 0x1FFFF) * KDIM + fl * 8);
      const uint4 v1 = *reinterpret_cast<const uint4*>(hb + (size_t)(r1.x & 0x1FFFF) * KDIM + fl * 8);
      const uint4 v2 = *reinterpret_cast<const uint4*>(hb + (size_t)(r2.x & 0x1FFFF) * KDIM + fl * 8);
      const uint4 v3 = *reinterpret_cast<const uint4*>(hb + (size_t)(r3.x & 0x1FFFF) * KDIM + fl * 8);
      const float w0 = __int_as_float(r0.y), w1 = __int_as_float(r1.y);
      const float w2 = __int_as_float(r2.y), w3 = __int_as_float(r3.y);
      a0 += bf_lo(v0.x) * w0 + bf_lo(v1.x) * w1 + bf_lo(v2.x) * w2 + bf_lo(v3.x) * w3;
      a1 += bf_hi(v0.x) * w0 + bf_hi(v1.x) * w1 + bf_hi(v2.x) * w2 + bf_hi(v3.x) * w3;
      a2 += bf_lo(v0.y) * w0 + bf_lo(v1.y) * w1 + bf_lo(v2.y) * w2 + bf_lo(v3.y) * w3;
      a3 += bf_hi(v0.y) * w0 + bf_hi(v1.y) * w1 + bf_hi(v2.y) * w2 + bf_hi(v3.y) * w3;
      a4 += bf_lo(v0.z) * w0 + bf_lo(v1.z) * w1 + bf_lo(v2.z) * w2 + bf_lo(v3.z) * w3;
      a5 += bf_hi(v0.z) * w0 + bf_hi(v1.z) * w1 + bf_hi(v2.z) * w2 + bf_hi(v3.z) * w3;
      a6 += bf_lo(v0.w) * w0 + bf_lo(v1.w) * w1 + bf_lo(v2.w) * w2 + bf_lo(v3.w) * w3;
      a7 += bf_hi(v0.w) * w0 + bf_hi(v1.w) * w1 + bf_hi(v2.w) * w2 + bf_hi(v3.w) * w3;
      ws += w0 + w1 + w2 + w3;
    }
    for (; j0 < re; j0 += 4) {               // tail: <=15 edges, predicated
      const int e = j0 + g;
      const bool act = e < re;
      const int2 r = lrec[act ? e : rs];     // rs valid (run non-empty here)
      const float w = act ? __int_as_float(r.y) : 0.f;
      const uint4 v = *reinterpret_cast<const uint4*>(hb + (size_t)(r.x & 0x1FFFF) * KDIM + fl * 8);
      a0 += bf_lo(v.x) * w; a1 += bf_hi(v.x) * w;
      a2 += bf_lo(v.y) * w; a3 += bf_hi(v.y) * w;
      a4 += bf_lo(v.z) * w; a5 += bf_hi(v.z) * w;
      a6 += bf_lo(v.w) * w; a7 += bf_hi(v.w) * w;
      ws += w;
    }
    // combine the 4 edge-groups (lanes fl, fl+16, fl+32, fl+48)
    a0 += __shfl_xor(a0, 16, 64); a0 += __shfl_xor(a0, 32, 64);
    a1 += __shfl_xor(a1, 16, 64); a1 += __shfl_xor(a1, 32, 64);
    a2 += __shfl_xor(a2, 16, 64); a2 += __shfl_xor(a2, 32, 64);
    a3 += __shfl_xor(a3, 16, 64); a3 += __shfl_xor(a3, 32, 64);
    a4 += __shfl_xor(a4, 16, 64); a4 += __shfl_xor(a4, 32, 64);
    a5 += __shfl_xor(a5, 16, 64); a5 += __shfl_xor(a5, 32, 64);
    a6 += __shfl_xor(a6, 16, 64); a6 += __shfl_xor(a6, 32, 64);
    a7 += __shfl_xor(a7, 16, 64); a7 += __shfl_xor(a7, 32, 64);
    ws += __shfl_xor(ws, 16, 64); ws += __shfl_xor(ws, 32, 64);
    const int node = blk * CB_NODES + wv * 16 + n;
    if (g == 0 && node < N) {
      const float inv = 1.0f / fmaxf(ws, EPS);
      uint4 o;
      o.x = pack2bf(a0 * inv, a1 * inv);
      o.y = pack2bf(a2 * inv, a3 * inv);
      o.z = pack2bf(a4 * inv, a5 * inv);
      o.w = pack2bf(a6 * inv, a7 * inv);
      *reinterpret_cast<uint4*>(hb + (size_t)node * KDIM + IN_DIM + fl * 8) = o;
    }
  }
}

// ---------------------------------------------------------------------------
// Slow path: bucket overflowed its region (never for this input). Recompute
// the whole bucket from the raw edge arrays with LDS f32 atomics. Early-exit
// sweep otherwise.
// ---------------------------------------------------------------------------
__global__ __launch_bounds__(512) void cagg_slow(
    unsigned short* __restrict__ hb, const int* __restrict__ gcursor,
    const int* __restrict__ src, const int* __restrict__ dstv,
    const float* __restrict__ ew, int N, int E) {
  const int blk = blockIdx.x;
  if (gcursor[blk] - blk * CAP_B <= CAP_B) return;
  __shared__ float agg[CB_NODES][IN_DIM];    // 64 KB
  __shared__ float wsum[CB_NODES];
  const int tid = threadIdx.x;
  const int lane = tid & 63;
  const int wv = tid >> 6;
  for (int i = tid; i < CB_NODES * IN_DIM; i += 512) (&agg[0][0])[i] = 0.f;
  if (tid < CB_NODES) wsum[tid] = 0.f;
  __syncthreads();
  for (int i = wv; i < E; i += 8) {          // one edge per wave
    const int s = src[i];
    if ((s >> 7) != blk) continue;
    const int sl = s & 127;
    const float w = ew[i];
    const unsigned v = *reinterpret_cast<const unsigned*>(
        hb + (size_t)dstv[i] * KDIM + lane * 2);
    atomicAdd(&agg[sl][lane * 2], bf_lo(v) * w);
    atomicAdd(&agg[sl][lane * 2 + 1], bf_hi(v) * w);
    if (lane == 0) atomicAdd(&wsum[sl], w);
  }
  __syncthreads();
  for (int n = 0; n < 16; ++n) {
    const int row = wv * 16 + n;
    const int node = blk * CB_NODES + row;
    if (node < N) {
      const float mm = fmaxf(wsum[row], EPS);
      *reinterpret_cast<unsigned*>(hb + (size_t)node * KDIM + IN_DIM + lane * 2) =
          pack2bf(agg[row][lane * 2] / mm, agg[row][lane * 2 + 1] / mm);
    }
  }
}

// ---------------------------------------------------------------------------
// MFMA GEMM: out = relu(hb @ W^T + b). Block = 256 rows x 256 cols, 8 waves.
// W staged f32->bf16 into XOR-swizzled LDS (cvt_w folded back in);
// A-frags preloaded to registers.
// ---------------------------------------------------------------------------
__global__ __launch_bounds__(512, 2) void sage_gemm_mfma(
    const unsigned short* __restrict__ hb,
    const float* __restrict__ W,
    const float* __restrict__ bias,
    float* __restrict__ out, int N) {
  __shared__ unsigned short Wl[OUT_DIM * KDIM];   // 128 KB, swizzled
  const int tid = threadIdx.x;
  const int lane = tid & 63;
  const int wv = tid >> 6;

  char* wl = reinterpret_cast<char*>(Wl);
  for (int ch = tid; ch < OUT_DIM * KDIM / 8; ch += 512) {
    const int elem = ch * 8;
    const int j = elem >> 8;          // W row 0..255
    const int col = elem & 255;       // multiple of 8
    const float4 w0 = *reinterpret_cast<const float4*>(W + elem);
    const float4 w1 = *reinterpret_cast<const float4*>(W + elem + 4);
    uint4 o;
    o.x = pack2bf(w0.x, w0.y); o.y = pack2bf(w0.z, w0.w);
    o.z = pack2bf(w1.x, w1.y); o.w = pack2bf(w1.z, w1.w);
    const int byte = (j << 9) | ((col * 2) ^ ((j & 7) << 4));
    *reinterpret_cast<uint4*>(wl + byte) = o;
  }

  const int row0 = blockIdx.x * 256 + wv * 32;
  const int kc = (lane >> 4) * 8;
  const unsigned short* arow0 = hb + (size_t)(row0 + (lane & 15)) * KDIM + kc;
  const unsigned short* arow1 = arow0 + 16 * KDIM;
  short8 a0[8], a1[8];
#pragma unroll
  for (int kk = 0; kk < 8; ++kk) {
    a0[kk] = *reinterpret_cast<const short8*>(arow0 + kk * 32);
    a1[kk] = *reinterpret_cast<const short8*>(arow1 + kk * 32);
  }

  __syncthreads();

  f32x4 acc[2][16];
#pragma unroll
  for (int i = 0; i < 2; ++i)
#pragma unroll
    for (int j = 0; j < 16; ++j) acc[i][j] = (f32x4){0.f, 0.f, 0.f, 0.f};

  const int jrow = lane & 15;
  const int kb0 = kc * 2;            // (lane>>4)*16
#pragma unroll
  for (int kk = 0; kk < 8; ++kk) {
    const int kbyte = kb0 + kk * 64;
#pragma unroll
    for (int ct = 0; ct < 16; ++ct) {
      const int j = ct * 16 + jrow;
      const short8 bf = *reinterpret_cast<const short8*>(
          wl + ((j << 9) | (kbyte ^ ((j & 7) << 4))));
      acc[0][ct] = __builtin_amdgcn_mfma_f32_16x16x32_bf16(a0[kk], bf, acc[0][ct], 0, 0, 0);
      acc[1][ct] = __builtin_amdgcn_mfma_f32_16x16x32_bf16(a1[kk], bf, acc[1][ct], 0, 0, 0);
    }
  }

  const int col = lane & 15;
  const int rquad = (lane >> 4) * 4;
#pragma unroll
  for (int ct = 0; ct < 16; ++ct) {
    const int j = ct * 16 + col;
    const float bj = bias[j];
#pragma unroll
    for (int rt = 0; rt < 2; ++rt) {
      const int rbase = row0 + rt * 16 + rquad;
      const f32x4 a = acc[rt][ct];
#pragma unroll
      for (int r = 0; r < 4; ++r) {
        const int row = rbase + r;
        if (row < N) out[(size_t)row * OUT_DIM + j] = fmaxf(a[r] + bj, 0.f);
      }
    }
  }
}

extern "C" void kernel_launch(void* const* d_in, const int* in_sizes, int n_in,
                              void* d_out, int out_size, void* d_ws, size_t ws_size,
                              hipStream_t stream) {
  const float* x  = (const float*)d_in[0];
  const int*   ei = (const int*)d_in[1];     // [2][E]
  const float* ew = (const float*)d_in[2];   // [E]
  const float* W  = (const float*)d_in[3];   // [OUT_DIM][KDIM]
  const float* b  = (const float*)d_in[4];   // [OUT_DIM]
  float* out = (float*)d_out;

  const int N = in_sizes[0] / IN_DIM;        // 100000
  const int E = in_sizes[2];                 // 1600000
  const int* src = ei;
  const int* dst = ei + E;

  const int gemm_blocks = (N + 255) / 256;   // 391
  const int Mpad = gemm_blocks * 256;        // 100096
  const int NB = (N + CB_NODES - 1) / CB_NODES;   // 782

  // ws layout (4-byte elems):
  //   hb[Mpad][256] bf16 | recs[NB*CAP_B] int2 | gcursor[NB_MAX]
  unsigned short* hb = (unsigned short*)d_ws;
  int2* recs   = (int2*)(hb + (size_t)Mpad * KDIM);
  int* gcursor = (int*)(recs + (size_t)NB * CAP_B);

  ginit<<<(NB + 255) / 256, 256, 0, stream>>>(gcursor, NB);
  cvt_x<<<2048, 256, 0, stream>>>(x, hb, N);
  cpartition<<<(E + PART_CHUNK - 1) / PART_CHUNK, 512, 0, stream>>>(
      src, dst, ew, gcursor, recs, E, NB);
  cagg_fast<<<NB, 512, 0, stream>>>(hb, gcursor, recs, N);
  cagg_slow<<<NB, 512, 0, stream>>>(hb, gcursor, src, dst, ew, N, E);
  sage_gemm_mfma<<<gemm_blocks, 512, 0, stream>>>(hb, W, b, out, N);
}